// Round 7
// baseline (308.428 us; speedup 1.0000x reference)
//
#include <hip/hip_runtime.h>
#include <hip/hip_bf16.h>
#include <math.h>

#define NB 8192   // B
#define ND 128    // D
#define N2 16384  // 2B

#define NRB 32    // 512-row blocks
#define NCB 64    // 256-col blocks
#define NTRI 1056 // sum_{R=0}^{31} (64-2R)

typedef __attribute__((ext_vector_type(8))) short short8;
typedef __attribute__((ext_vector_type(4))) float f32x4;

// sqrt((1/T) * log2(e)) with T=0.5 : sqrt(2.8853900817779268)
static constexpr float SQRT_C_VAL = 1.69864368f;

__device__ inline unsigned short f2bf(float f) {
    __hip_bfloat16 h = __float2bfloat16(f);
    return __builtin_bit_cast(unsigned short, h);
}

// ---------------- normalize + positive-pair dot ----------------
__global__ __launch_bounds__(256) void nrm_kernel(const float* __restrict__ zi,
                                                  const float* __restrict__ zj,
                                                  unsigned int* __restrict__ reps_u32,
                                                  float* __restrict__ pos) {
    const int pair = (int)((blockIdx.x * 256 + threadIdx.x) >> 6);
    const int lane = threadIdx.x & 63;
    const float2 vi = *reinterpret_cast<const float2*>(zi + pair * ND + lane * 2);
    const float2 vj = *reinterpret_cast<const float2*>(zj + pair * ND + lane * 2);
    float ssi = vi.x * vi.x + vi.y * vi.y;
    float ssj = vj.x * vj.x + vj.y * vj.y;
#pragma unroll
    for (int m = 1; m < 64; m <<= 1) {
        ssi += __shfl_xor(ssi, m);
        ssj += __shfl_xor(ssj, m);
    }
    float ni = fmaxf(sqrtf(ssi), 1e-12f);
    float nj = fmaxf(sqrtf(ssj), 1e-12f);
    const float ii = 1.0f / ni, ij = 1.0f / nj;
    const float uix = vi.x * ii, uiy = vi.y * ii;
    const float ujx = vj.x * ij, ujy = vj.y * ij;
    float d = uix * ujx + uiy * ujy;
#pragma unroll
    for (int m = 1; m < 64; m <<= 1) d += __shfl_xor(d, m);
    if (lane == 0) pos[pair] = d;
    const unsigned int pi =
        (unsigned int)f2bf(uix * SQRT_C_VAL) | ((unsigned int)f2bf(uiy * SQRT_C_VAL) << 16);
    const unsigned int pj =
        (unsigned int)f2bf(ujx * SQRT_C_VAL) | ((unsigned int)f2bf(ujy * SQRT_C_VAL) << 16);
    reps_u32[pair * 64 + lane] = pi;
    reps_u32[(NB + pair) * 64 + lane] = pj;
}

// ---------------- fused sim-GEMM + sum(exp2), upper-triangle, 8-wave blocks ----------------
__device__ inline void gload_lds16(const void* g, void* l) {
    __builtin_amdgcn_global_load_lds(
        (const __attribute__((address_space(1))) void*)g,
        (__attribute__((address_space(3))) void*)l, 16, 0, 0);
}

__global__ __launch_bounds__(512, 4) void sim_kernel(const char* __restrict__ reps,
                                                     float* __restrict__ ssum) {
    __shared__ __align__(16) char lds[256 * 256];  // 64 KiB K-panel (256 cols x 256 B)
    const int tid = threadIdx.x;
    const int lane = tid & 63;
    const int wid = tid >> 6;
    const int l15 = lane & 15;
    const int l4 = lane >> 4;

    // linear id -> (R, C): R in [0,32), C in [2R, 64). start(R) = R*(65-R)
    const int t = blockIdx.x;
    int R = (int)((65.0f - sqrtf(4225.0f - 4.0f * (float)t)) * 0.5f);
    while (R > 0 && R * (65 - R) > t) --R;
    while ((R + 1) * (64 - R) <= t) ++R;
    const int C = 2 * R + (t - R * (65 - R));

    const int qb = R * 512 + wid * 64;   // this wave's 64 rows
    const int cbase = C * 256;           // this block's 256 cols
    const int a = qb >> 8;               // this wave's 256-row-block index
    const bool skip = (a > C);           // lower-triangle duplicate sub-tile
    const bool diag = (a == C);          // self tile: mask row==col, row-sums only

    // stage the 256-col K-panel once (4096 16B slots / 512 threads = 8 each)
#pragma unroll
    for (int q = 0; q < 8; ++q) {
        const int s = q * 512 + tid;  // slot 0..4095
        const int r = s >> 4, c = s & 15;
        // pre-swizzled global source (rule #21): LDS linear, slot (r,c) <- chunk (r, c^(r&15))
        const char* src = reps + (size_t)(cbase + r) * 256 + ((c ^ (r & 15)) * 16);
        char* dst = &lds[(q * 512 + wid * 64) * 16];  // wave-uniform base
        gload_lds16(src, dst);
    }

    // Q fragments resident: 4 row-groups x 4 k-chunks
    short8 qf[4][4];
    if (!skip) {
#pragma unroll
        for (int g = 0; g < 4; ++g)
#pragma unroll
            for (int kk = 0; kk < 4; ++kk)
                qf[g][kk] = *reinterpret_cast<const short8*>(
                    reps + (size_t)(qb + g * 16 + l15) * 256 + l4 * 16 + kk * 64);
    }

    float sacc[4][4];
#pragma unroll
    for (int g = 0; g < 4; ++g)
#pragma unroll
        for (int r = 0; r < 4; ++r) sacc[g][r] = 0.f;

    __syncthreads();  // panel ready (drains vmcnt)
    if (skip) return;

#pragma unroll 4
    for (int cg = 0; cg < 16; ++cg) {
        const int kr = cg * 16 + l15;
        const char* lb = &lds[kr * 256];
        short8 kf[4];
#pragma unroll
        for (int kk = 0; kk < 4; ++kk)
            kf[kk] = *reinterpret_cast<const short8*>(lb + (((kk * 4 + l4) ^ (kr & 15)) * 16));
        float csum = 0.f;
#pragma unroll
        for (int g = 0; g < 4; ++g) {
            f32x4 acc = {0.f, 0.f, 0.f, 0.f};
#pragma unroll
            for (int kk = 0; kk < 4; ++kk)
                acc = __builtin_amdgcn_mfma_f32_16x16x32_bf16(qf[g][kk], kf[kk], acc, 0, 0, 0);
            if (diag) {
                const int col = cbase + cg * 16 + l15;
                const int row0 = qb + g * 16 + l4 * 4;
#pragma unroll
                for (int r = 0; r < 4; ++r) {
                    const float e = __builtin_amdgcn_exp2f(acc[r]);
                    sacc[g][r] += (row0 + r == col) ? 0.f : e;
                }
            } else {
#pragma unroll
                for (int r = 0; r < 4; ++r) {
                    const float e = __builtin_amdgcn_exp2f(acc[r]);
                    sacc[g][r] += e;
                    csum += e;
                }
            }
        }
        if (!diag) {
            // column sums (this wave's 64 rows): reduce over the 4 row-groups (l4)
            csum += __shfl_xor(csum, 16);
            csum += __shfl_xor(csum, 32);
            if (lane < 16) atomicAdd(&ssum[cbase + cg * 16 + lane], csum);
        }
    }

    // row sums: reduce across the 16 column-lanes, then one atomic per row
#pragma unroll
    for (int g = 0; g < 4; ++g)
#pragma unroll
        for (int r = 0; r < 4; ++r) {
#pragma unroll
            for (int m = 1; m < 16; m <<= 1) sacc[g][r] += __shfl_xor(sacc[g][r], m);
        }
    if (l15 == 0) {
#pragma unroll
        for (int g = 0; g < 4; ++g)
#pragma unroll
            for (int r = 0; r < 4; ++r)
                atomicAdd(&ssum[qb + g * 16 + l4 * 4 + r], sacc[g][r]);
    }
}

// ---------------- finalize: loss = mean(ln(ssum) - 2*pos) ----------------
__global__ __launch_bounds__(1024) void fin_kernel(const float* __restrict__ ssum,
                                                   const float* __restrict__ pos,
                                                   float* __restrict__ out) {
    const int tid = threadIdx.x;
    float acc = 0.f;
    for (int r = tid; r < N2; r += 1024) {
        const int p = (r < NB) ? r : r - NB;
        acc += logf(ssum[r]) - 2.0f * pos[p];
    }
#pragma unroll
    for (int m = 1; m < 64; m <<= 1) acc += __shfl_xor(acc, m);
    __shared__ float red[16];
    const int wid = tid >> 6, lane = tid & 63;
    if (lane == 0) red[wid] = acc;
    __syncthreads();
    if (wid == 0) {
        float v = (lane < 16) ? red[lane] : 0.f;
#pragma unroll
        for (int m = 1; m < 16; m <<= 1) v += __shfl_xor(v, m);
        if (lane == 0) out[0] = v / (float)N2;
    }
}

extern "C" void kernel_launch(void* const* d_in, const int* in_sizes, int n_in,
                              void* d_out, int out_size, void* d_ws, size_t ws_size,
                              hipStream_t stream) {
    const float* zi = (const float*)d_in[0];
    const float* zj = (const float*)d_in[1];
    float* out = (float*)d_out;
    char* ws = (char*)d_ws;

    char* reps = ws;                                       // 16384*128*2 = 4 MiB bf16
    float* pos = (float*)(ws + (size_t)N2 * ND * 2);       // 8192 f32
    float* ssum = pos + NB;                                // 16384 f32

    (void)hipMemsetAsync(ssum, 0, N2 * sizeof(float), stream);
    nrm_kernel<<<NB / 4, 256, 0, stream>>>(zi, zj, (unsigned int*)reps, pos);
    sim_kernel<<<NTRI, 512, 0, stream>>>(reps, ssum);
    fin_kernel<<<1, 1024, 0, stream>>>(ssum, pos, out);
}

// Round 8
// 111.281 us; speedup vs baseline: 2.7716x; 2.7716x over previous
//
#include <hip/hip_runtime.h>
#include <hip/hip_bf16.h>
#include <math.h>

#define NB 8192   // B
#define ND 128    // D
#define N2 16384  // 2B

#define NRB 32    // 512-row blocks
#define NCB 64    // 256-col blocks
#define NTRI 1056 // sum_{R=0}^{31} (64-2R)

typedef __attribute__((ext_vector_type(8))) short short8;
typedef __attribute__((ext_vector_type(4))) float f32x4;

// sqrt((1/T) * log2(e)) with T=0.5 : sqrt(2.8853900817779268)
static constexpr float SQRT_C_VAL = 1.69864368f;

__device__ inline unsigned short f2bf(float f) {
    __hip_bfloat16 h = __float2bfloat16(f);
    return __builtin_bit_cast(unsigned short, h);
}

// ---------------- normalize + positive-pair dot ----------------
__global__ __launch_bounds__(256) void nrm_kernel(const float* __restrict__ zi,
                                                  const float* __restrict__ zj,
                                                  unsigned int* __restrict__ reps_u32,
                                                  float* __restrict__ pos) {
    const int pair = (int)((blockIdx.x * 256 + threadIdx.x) >> 6);
    const int lane = threadIdx.x & 63;
    const float2 vi = *reinterpret_cast<const float2*>(zi + pair * ND + lane * 2);
    const float2 vj = *reinterpret_cast<const float2*>(zj + pair * ND + lane * 2);
    float ssi = vi.x * vi.x + vi.y * vi.y;
    float ssj = vj.x * vj.x + vj.y * vj.y;
#pragma unroll
    for (int m = 1; m < 64; m <<= 1) {
        ssi += __shfl_xor(ssi, m);
        ssj += __shfl_xor(ssj, m);
    }
    float ni = fmaxf(sqrtf(ssi), 1e-12f);
    float nj = fmaxf(sqrtf(ssj), 1e-12f);
    const float ii = 1.0f / ni, ij = 1.0f / nj;
    const float uix = vi.x * ii, uiy = vi.y * ii;
    const float ujx = vj.x * ij, ujy = vj.y * ij;
    float d = uix * ujx + uiy * ujy;
#pragma unroll
    for (int m = 1; m < 64; m <<= 1) d += __shfl_xor(d, m);
    if (lane == 0) pos[pair] = d;
    const unsigned int pi =
        (unsigned int)f2bf(uix * SQRT_C_VAL) | ((unsigned int)f2bf(uiy * SQRT_C_VAL) << 16);
    const unsigned int pj =
        (unsigned int)f2bf(ujx * SQRT_C_VAL) | ((unsigned int)f2bf(ujy * SQRT_C_VAL) << 16);
    reps_u32[pair * 64 + lane] = pi;
    reps_u32[(NB + pair) * 64 + lane] = pj;
}

// ---------------- fused sim-GEMM + sum(exp2), upper-triangle, 8-wave blocks ----------------
__device__ inline void gload_lds16(const void* g, void* l) {
    __builtin_amdgcn_global_load_lds(
        (const __attribute__((address_space(1))) void*)g,
        (__attribute__((address_space(3))) void*)l, 16, 0, 0);
}

__global__ __launch_bounds__(512, 2) void sim_kernel(const char* __restrict__ reps,
                                                     float* __restrict__ ssum) {
    __shared__ __align__(16) char lds[256 * 256];  // 64 KiB K-panel (256 cols x 256 B)
    const int tid = threadIdx.x;
    const int lane = tid & 63;
    const int wid = tid >> 6;
    const int l15 = lane & 15;
    const int l4 = lane >> 4;

    // linear id -> (R, C): R in [0,32), C in [2R, 64). start(R) = R*(65-R)
    const int t = blockIdx.x;
    int R = (int)((65.0f - sqrtf(4225.0f - 4.0f * (float)t)) * 0.5f);
    while (R > 0 && R * (65 - R) > t) --R;
    while ((R + 1) * (64 - R) <= t) ++R;
    const int C = 2 * R + (t - R * (65 - R));

    const int qb = R * 512 + wid * 64;   // this wave's 64 rows
    const int cbase = C * 256;           // this block's 256 cols
    const int a = qb >> 8;               // this wave's 256-row-block index
    const bool skip = (a > C);           // lower-triangle duplicate sub-tile
    const bool diag = (a == C);          // self tile: mask row==col, row-sums only

    // stage the 256-col K-panel once (4096 16B slots / 512 threads = 8 each)
#pragma unroll
    for (int q = 0; q < 8; ++q) {
        const int s = q * 512 + tid;  // slot 0..4095
        const int r = s >> 4, c = s & 15;
        // pre-swizzled global source (rule #21): LDS linear, slot (r,c) <- chunk (r, c^(r&15))
        const char* src = reps + (size_t)(cbase + r) * 256 + ((c ^ (r & 15)) * 16);
        char* dst = &lds[(q * 512 + wid * 64) * 16];  // wave-uniform base
        gload_lds16(src, dst);
    }

    // Q fragments resident: 4 row-groups x 4 k-chunks
    short8 qf[4][4];
    if (!skip) {
#pragma unroll
        for (int g = 0; g < 4; ++g)
#pragma unroll
            for (int kk = 0; kk < 4; ++kk)
                qf[g][kk] = *reinterpret_cast<const short8*>(
                    reps + (size_t)(qb + g * 16 + l15) * 256 + l4 * 16 + kk * 64);
    }

    float sacc[4][4];
#pragma unroll
    for (int g = 0; g < 4; ++g)
#pragma unroll
        for (int r = 0; r < 4; ++r) sacc[g][r] = 0.f;

    __syncthreads();  // panel ready (drains vmcnt)
    if (skip) return;

#pragma unroll 4
    for (int cg = 0; cg < 16; ++cg) {
        const int kr = cg * 16 + l15;
        const char* lb = &lds[kr * 256];
        short8 kf[4];
#pragma unroll
        for (int kk = 0; kk < 4; ++kk)
            kf[kk] = *reinterpret_cast<const short8*>(lb + (((kk * 4 + l4) ^ (kr & 15)) * 16));
        float csum = 0.f;
#pragma unroll
        for (int g = 0; g < 4; ++g) {
            f32x4 acc = {0.f, 0.f, 0.f, 0.f};
#pragma unroll
            for (int kk = 0; kk < 4; ++kk)
                acc = __builtin_amdgcn_mfma_f32_16x16x32_bf16(qf[g][kk], kf[kk], acc, 0, 0, 0);
            if (diag) {
                const int col = cbase + cg * 16 + l15;
                const int row0 = qb + g * 16 + l4 * 4;
#pragma unroll
                for (int r = 0; r < 4; ++r) {
                    const float e = __builtin_amdgcn_exp2f(acc[r]);
                    sacc[g][r] += (row0 + r == col) ? 0.f : e;
                }
            } else {
#pragma unroll
                for (int r = 0; r < 4; ++r) {
                    const float e = __builtin_amdgcn_exp2f(acc[r]);
                    sacc[g][r] += e;
                    csum += e;
                }
            }
        }
        if (!diag) {
            // column sums (this wave's 64 rows): reduce over the 4 row-groups (l4)
            csum += __shfl_xor(csum, 16);
            csum += __shfl_xor(csum, 32);
            if (lane < 16) atomicAdd(&ssum[cbase + cg * 16 + lane], csum);
        }
    }

    // row sums: reduce across the 16 column-lanes, then one atomic per row
#pragma unroll
    for (int g = 0; g < 4; ++g)
#pragma unroll
        for (int r = 0; r < 4; ++r) {
#pragma unroll
            for (int m = 1; m < 16; m <<= 1) sacc[g][r] += __shfl_xor(sacc[g][r], m);
        }
    if (l15 == 0) {
#pragma unroll
        for (int g = 0; g < 4; ++g)
#pragma unroll
            for (int r = 0; r < 4; ++r)
                atomicAdd(&ssum[qb + g * 16 + l4 * 4 + r], sacc[g][r]);
    }
}

// ---------------- finalize: loss = mean(ln(ssum) - 2*pos) ----------------
__global__ __launch_bounds__(1024) void fin_kernel(const float* __restrict__ ssum,
                                                   const float* __restrict__ pos,
                                                   float* __restrict__ out) {
    const int tid = threadIdx.x;
    float acc = 0.f;
    for (int r = tid; r < N2; r += 1024) {
        const int p = (r < NB) ? r : r - NB;
        acc += logf(ssum[r]) - 2.0f * pos[p];
    }
#pragma unroll
    for (int m = 1; m < 64; m <<= 1) acc += __shfl_xor(acc, m);
    __shared__ float red[16];
    const int wid = tid >> 6, lane = tid & 63;
    if (lane == 0) red[wid] = acc;
    __syncthreads();
    if (wid == 0) {
        float v = (lane < 16) ? red[lane] : 0.f;
#pragma unroll
        for (int m = 1; m < 16; m <<= 1) v += __shfl_xor(v, m);
        if (lane == 0) out[0] = v / (float)N2;
    }
}

extern "C" void kernel_launch(void* const* d_in, const int* in_sizes, int n_in,
                              void* d_out, int out_size, void* d_ws, size_t ws_size,
                              hipStream_t stream) {
    const float* zi = (const float*)d_in[0];
    const float* zj = (const float*)d_in[1];
    float* out = (float*)d_out;
    char* ws = (char*)d_ws;

    char* reps = ws;                                       // 16384*128*2 = 4 MiB bf16
    float* pos = (float*)(ws + (size_t)N2 * ND * 2);       // 8192 f32
    float* ssum = pos + NB;                                // 16384 f32

    (void)hipMemsetAsync(ssum, 0, N2 * sizeof(float), stream);
    nrm_kernel<<<NB / 4, 256, 0, stream>>>(zi, zj, (unsigned int*)reps, pos);
    sim_kernel<<<NTRI, 512, 0, stream>>>(reps, ssum);
    fin_kernel<<<1, 1024, 0, stream>>>(ssum, pos, out);
}

// Round 9
// 89.191 us; speedup vs baseline: 3.4581x; 1.2477x over previous
//
#include <hip/hip_runtime.h>
#include <hip/hip_bf16.h>

#define NB 8192   // B
#define ND 128    // D
#define N2 16384  // 2B

#define CPB 1024              // columns per block (16-way column split)
#define CTILE 64              // columns staged per LDS tile
#define NT (CPB / CTILE)      // 16 tiles per block

typedef __attribute__((ext_vector_type(8))) short short8;
typedef __attribute__((ext_vector_type(4))) float f32x4;

// sqrt((1/T) * log2(e)) with T=0.5 : sqrt(2.8853900817779268)
static constexpr float SQRT_C_VAL = 1.69864368f;

__device__ inline unsigned short f2bf(float f) {
    __hip_bfloat16 h = __float2bfloat16(f);
    return __builtin_bit_cast(unsigned short, h);
}

// ---------------- normalize + positive-pair dot ----------------
__global__ __launch_bounds__(256) void nrm_kernel(const float* __restrict__ zi,
                                                  const float* __restrict__ zj,
                                                  unsigned int* __restrict__ reps_u32,
                                                  float* __restrict__ pos) {
    const int pair = (int)((blockIdx.x * 256 + threadIdx.x) >> 6);
    const int lane = threadIdx.x & 63;
    const float2 vi = *reinterpret_cast<const float2*>(zi + pair * ND + lane * 2);
    const float2 vj = *reinterpret_cast<const float2*>(zj + pair * ND + lane * 2);
    float ssi = vi.x * vi.x + vi.y * vi.y;
    float ssj = vj.x * vj.x + vj.y * vj.y;
#pragma unroll
    for (int m = 1; m < 64; m <<= 1) {
        ssi += __shfl_xor(ssi, m);
        ssj += __shfl_xor(ssj, m);
    }
    float ni = fmaxf(sqrtf(ssi), 1e-12f);
    float nj = fmaxf(sqrtf(ssj), 1e-12f);
    const float ii = 1.0f / ni, ij = 1.0f / nj;
    const float uix = vi.x * ii, uiy = vi.y * ii;
    const float ujx = vj.x * ij, ujy = vj.y * ij;
    float d = uix * ujx + uiy * ujy;
#pragma unroll
    for (int m = 1; m < 64; m <<= 1) d += __shfl_xor(d, m);
    if (lane == 0) pos[pair] = d;
    const unsigned int pi =
        (unsigned int)f2bf(uix * SQRT_C_VAL) | ((unsigned int)f2bf(uiy * SQRT_C_VAL) << 16);
    const unsigned int pj =
        (unsigned int)f2bf(ujx * SQRT_C_VAL) | ((unsigned int)f2bf(ujy * SQRT_C_VAL) << 16);
    reps_u32[pair * 64 + lane] = pi;
    reps_u32[(NB + pair) * 64 + lane] = pj;
}

// ---------------- fused sim-GEMM + sum(exp2), 8 waves x 32 rows ----------------
__device__ inline void gload_lds16(const void* g, void* l) {
    __builtin_amdgcn_global_load_lds(
        (const __attribute__((address_space(1))) void*)g,
        (__attribute__((address_space(3))) void*)l, 16, 0, 0);
}

__global__ __launch_bounds__(512, 3) void sim_kernel(const char* __restrict__ reps,
                                                     float* __restrict__ ssum) {
    __shared__ __align__(16) char lds[2][CTILE * 256];  // 2 x 16 KiB
    const int tid = threadIdx.x;
    const int lane = tid & 63;
    const int wid = tid >> 6;       // 0..7
    const int l15 = lane & 15;
    const int l4 = lane >> 4;
    const int rb = blockIdx.x * 256;  // 256 rows per block
    const int cb = blockIdx.y * CPB;  // column split
    const int qb = rb + wid * 32;     // this wave's 32 rows

    // Q fragments resident: 2 row-groups x 4 k-chunks (32 VGPRs)
    short8 qf[2][4];
#pragma unroll
    for (int g = 0; g < 2; ++g)
#pragma unroll
        for (int kk = 0; kk < 4; ++kk)
            qf[g][kk] = *reinterpret_cast<const short8*>(
                reps + (size_t)(qb + g * 16 + l15) * 256 + l4 * 16 + kk * 64);

    float sacc[2][4];
#pragma unroll
    for (int g = 0; g < 2; ++g)
#pragma unroll
        for (int r = 0; r < 4; ++r) sacc[g][r] = 0.f;

    auto stage = [&](int buf, int t) {
        const int colbase = cb + t * CTILE;
#pragma unroll
        for (int q = 0; q < 2; ++q) {
            const int s = q * 512 + tid;  // 16B slot 0..1023
            const int r = s >> 4, c = s & 15;
            // pre-swizzled global source (rule #21): LDS linear, slot (r,c) <- chunk (r, c^(r&15))
            const char* src = reps + (size_t)(colbase + r) * 256 + ((c ^ (r & 15)) * 16);
            char* dst = &lds[buf][(q * 512 + wid * 64) * 16];  // wave-uniform base
            gload_lds16(src, dst);
        }
    };

    auto compute = [&](int buf, int tc) {
        const bool dg = ((unsigned)(qb - tc) < 64u);  // wave rows overlap this 64-col tile
#pragma unroll
        for (int cg = 0; cg < 4; ++cg) {
            const int kr = cg * 16 + l15;
            const char* lb = &lds[buf][kr * 256];
            short8 kf[4];
#pragma unroll
            for (int kk = 0; kk < 4; ++kk)
                kf[kk] = *reinterpret_cast<const short8*>(lb + (((kk * 4 + l4) ^ (kr & 15)) * 16));
#pragma unroll
            for (int g = 0; g < 2; ++g) {
                f32x4 acc = {0.f, 0.f, 0.f, 0.f};
#pragma unroll
                for (int kk = 0; kk < 4; ++kk)
                    acc = __builtin_amdgcn_mfma_f32_16x16x32_bf16(qf[g][kk], kf[kk], acc, 0, 0, 0);
                if (!dg) {
#pragma unroll
                    for (int r = 0; r < 4; ++r) sacc[g][r] += __builtin_amdgcn_exp2f(acc[r]);
                } else {
                    const int col = tc + cg * 16 + l15;
                    const int row0 = qb + g * 16 + l4 * 4;
#pragma unroll
                    for (int r = 0; r < 4; ++r) {
                        const float e = __builtin_amdgcn_exp2f(acc[r]);
                        sacc[g][r] += (row0 + r == col) ? 0.f : e;
                    }
                }
            }
        }
    };

    stage(0, 0);
    __syncthreads();
    int cur = 0;
    for (int t = 0; t < NT; ++t) {
        if (t + 1 < NT) stage(cur ^ 1, t + 1);
        compute(cur, cb + t * CTILE);
        __syncthreads();
        cur ^= 1;
    }

    // reduce across the 16 column-lanes, then one atomic per row
#pragma unroll
    for (int g = 0; g < 2; ++g)
#pragma unroll
        for (int r = 0; r < 4; ++r) {
#pragma unroll
            for (int m = 1; m < 16; m <<= 1) sacc[g][r] += __shfl_xor(sacc[g][r], m);
        }
    if (l15 == 0) {
#pragma unroll
        for (int g = 0; g < 2; ++g)
#pragma unroll
            for (int r = 0; r < 4; ++r)
                atomicAdd(&ssum[qb + g * 16 + l4 * 4 + r], sacc[g][r]);
    }
}

// ---------------- finalize: loss = mean(ln(ssum) - 2*pos) ----------------
__global__ __launch_bounds__(1024) void fin_kernel(const float* __restrict__ ssum,
                                                   const float* __restrict__ pos,
                                                   float* __restrict__ out) {
    const int tid = threadIdx.x;
    float acc = 0.f;
    for (int r = tid; r < N2; r += 1024) {
        const int p = (r < NB) ? r : r - NB;
        acc += logf(ssum[r]) - 2.0f * pos[p];
    }
#pragma unroll
    for (int m = 1; m < 64; m <<= 1) acc += __shfl_xor(acc, m);
    __shared__ float red[16];
    const int wid = tid >> 6, lane = tid & 63;
    if (lane == 0) red[wid] = acc;
    __syncthreads();
    if (wid == 0) {
        float v = (lane < 16) ? red[lane] : 0.f;
#pragma unroll
        for (int m = 1; m < 16; m <<= 1) v += __shfl_xor(v, m);
        if (lane == 0) out[0] = v / (float)N2;
    }
}

extern "C" void kernel_launch(void* const* d_in, const int* in_sizes, int n_in,
                              void* d_out, int out_size, void* d_ws, size_t ws_size,
                              hipStream_t stream) {
    const float* zi = (const float*)d_in[0];
    const float* zj = (const float*)d_in[1];
    float* out = (float*)d_out;
    char* ws = (char*)d_ws;

    char* reps = ws;                                       // 16384*128*2 = 4 MiB bf16
    float* pos = (float*)(ws + (size_t)N2 * ND * 2);       // 8192 f32
    float* ssum = pos + NB;                                // 16384 f32

    (void)hipMemsetAsync(ssum, 0, N2 * sizeof(float), stream);
    nrm_kernel<<<NB / 4, 256, 0, stream>>>(zi, zj, (unsigned int*)reps, pos);
    dim3 grid(N2 / 256, N2 / CPB);
    sim_kernel<<<grid, 512, 0, stream>>>(reps, ssum);
    fin_kernel<<<1, 1024, 0, stream>>>(ssum, pos, out);
}